// Round 4
// baseline (652.820 us; speedup 1.0000x reference)
//
#include <hip/hip_runtime.h>
#include <cstdint>
#include <cstddef>

// Problem constants (fixed by reference: x (4,2048,4096) f32, weight (4096,4096) f32)
#define MDIM 8192
#define NDIM 4096
#define KDIM 4096
#define TERN_THRESH 0.1f

typedef unsigned short u16;
typedef __bf16 bf16x8 __attribute__((ext_vector_type(8)));
typedef float f32x4 __attribute__((ext_vector_type(4)));
typedef u16 u16x4 __attribute__((ext_vector_type(4)));
typedef u16 u16x8 __attribute__((ext_vector_type(8)));

// ---------------------------------------------------------------- helpers ---

__device__ __forceinline__ u16 f2bf(float f) {
  // round-to-nearest-even f32 -> bf16 (inputs are finite, no NaN handling)
  unsigned u = __float_as_uint(f);
  u += 0x7FFFu + ((u >> 16) & 1u);
  return (u16)(u >> 16);
}

__device__ __forceinline__ u16 tern_bf16(float w) {
  // sign(w) * (|w| > 0.1)  as bf16 bits: +1=0x3F80, -1=0xBF80, 0=0
  return w > TERN_THRESH ? (u16)0x3F80u : (w < -TERN_THRESH ? (u16)0xBF80u : (u16)0u);
}

// async global -> LDS, 16 B per lane; LDS side is wave-uniform base + lane*16
__device__ __forceinline__ void load_lds16(const u16* g, u16* s) {
  __builtin_amdgcn_global_load_lds(
      (__attribute__((address_space(1))) void*)(void*)(g),
      (__attribute__((address_space(3))) void*)(void*)(s),
      16, 0, 0);
}

// ------------------------------------------------------- conversion kernel ---
// R4: dropped __builtin_nontemporal_load. R3's contiguous-vs-strided change was
// a NO-OP (residual 213us both ways) -> access pattern was never the limiter;
// the shared factor was NT loads (suspected L2-bypass: per-lane requests reach
// HBM uncoalesced, and x+w (201 MB, L3-fits) get re-fetched from HBM every
// iteration). Plain cached loads restore coalescing + L3 residency. Same
// element math -> identical output bytes.

#define XBLOCKS ((MDIM * (size_t)KDIM) / (8 * 256))   // 16384
#define WBLOCKS ((NDIM * (size_t)KDIM) / (8 * 256))   //  8192

__global__ __launch_bounds__(256) void cvt_kernel(const float* __restrict__ x,
                                                  u16* __restrict__ xb,
                                                  const float* __restrict__ w,
                                                  u16* __restrict__ qb) {
  size_t b = blockIdx.x;
  if (b < XBLOCKS) {
    size_t i0 = b * 512 + threadIdx.x;   // f32x4 index, lane-contiguous
    size_t i1 = i0 + 256;
    const f32x4* x4 = (const f32x4*)x;
    f32x4 a = x4[i0];
    f32x4 c = x4[i1];
    u16x4 oa, oc;
    oa[0] = f2bf(a[0]); oa[1] = f2bf(a[1]); oa[2] = f2bf(a[2]); oa[3] = f2bf(a[3]);
    oc[0] = f2bf(c[0]); oc[1] = f2bf(c[1]); oc[2] = f2bf(c[2]); oc[3] = f2bf(c[3]);
    ((u16x4*)xb)[i0] = oa;
    ((u16x4*)xb)[i1] = oc;
  } else {
    size_t i0 = (b - XBLOCKS) * 512 + threadIdx.x;
    size_t i1 = i0 + 256;
    const f32x4* w4 = (const f32x4*)w;
    f32x4 a = w4[i0];
    f32x4 c = w4[i1];
    u16x4 oa, oc;
    oa[0] = tern_bf16(a[0]); oa[1] = tern_bf16(a[1]); oa[2] = tern_bf16(a[2]); oa[3] = tern_bf16(a[3]);
    oc[0] = tern_bf16(c[0]); oc[1] = tern_bf16(c[1]); oc[2] = tern_bf16(c[2]); oc[3] = tern_bf16(c[3]);
    ((u16x4*)qb)[i0] = oa;
    ((u16x4*)qb)[i1] = oc;
  }
}

// ---------------------------------------------------------------- GEMM ------
// R4: B-operand DIRECT TO REGISTERS (flatmm-style). R1-R3 all pinned at
// MfmaUtil ~50%: per tile per CU, LDS pipe (96 ds_read_b128 ~12cyc + 32KB
// stage writes ~ 1400 cyc) vs MFMA pipe (1242 cyc) barely overlap -> LDS is
// co-critical. Removing B from LDS cuts reads 12->8/wave/tile and writes in
// half: LDS pipe ~900 cyc < MFMA 1242 -> MFMA becomes the sole critical pipe.
//
// B frags: per wave per tile, 4x per-lane global bf16x8 loads
//   Qb[(colBase + wn*64 + j*16 + l16)*K + kb + quad*8]
// (identical bytes the LDS path delivered: B-frag lane l = col l&15, k =
// quad*8..+8). Double-buffered reg sets (bcur/bnxt), prefetched 1 tile ahead
// (~1700 cyc issue->use >> L2 latency). B panels are XCD-local (swizzle) ->
// served from L2 (~10 TB/s demand vs 34.5 ceiling).
//
// A staging: unchanged 4-slot LDS ring (now 64 KiB total), 3-tile lead.
// vmcnt ledger (vmcnt is an IN-ORDER FIFO): per tile issues, in pinned order,
// [A-stage(t+3) x2, FENCE, B(t+1) x4]. VMCNT6 at tile end leaves at most the
// 6 newest = {A(t+3)x2, B(t+1)x4} -> A(t+1), A(t+2), B(t) all retired; hence
// A(t+1) is LDS-resident one full tile before tile t+1's preload reads it
// (guaranteed by the END-OF-(t-1) wait). Compiler auto-waits for B-reg uses
// add only tighter (older-inclusive) waits -> harmless. Prologue: stage
// A(0),A(1),A(2) + load B(0); vmcnt(8) retires A(0).
// Tail: t+3>=NTILE stages k=0 into dead slots; t=127 loads dummy B(k=0) into
// the dead ping-pong set. Accumulation order per acc element: tiles
// ascending, one MFMA each -> bit-identical to R2/R3 (absmax preserved).
//
// LDS slot layout (A only, 16 KB/slot): [256 rows][4 chunks of 16B], linear
// chunk c holds global (row = c>>2, kchunk = (c&3) ^ ((row>>1)&3)). Global
// source pre-swizzled, LDS dest linear (global_load_lds rule), same XOR on
// read -> quad's 16 lanes hit all 8 16B-slots 2x = conflict-free (R1-R3: 0).

#define NTILE (KDIM / 32)   // 128

#define BARRIER() __builtin_amdgcn_s_barrier()
#define FENCE()   asm volatile("" ::: "memory")
#define VMCNT6()  asm volatile("s_waitcnt vmcnt(6)" ::: "memory")
#define VMCNT8()  asm volatile("s_waitcnt vmcnt(8)" ::: "memory")

#define MFMA16(AF, BF, I0)                                                   \
  do {                                                                       \
    _Pragma("unroll") for (int _i = 0; _i < 4; ++_i) {                       \
      _Pragma("unroll") for (int _j = 0; _j < 4; ++_j) {                     \
        acc[(I0) + _i][_j] = __builtin_amdgcn_mfma_f32_16x16x32_bf16(        \
            AF[_i], BF[_j], acc[(I0) + _i][_j], 0, 0, 0);                    \
      }                                                                      \
    }                                                                        \
  } while (0)

__global__ __launch_bounds__(512, 2) void gemm_tern_kernel(
    const u16* __restrict__ Xb,     // [MDIM][KDIM] bf16 bits
    const u16* __restrict__ Qb,     // [NDIM][KDIM] bf16 bits
    const float* __restrict__ bias, // [NDIM]
    float* __restrict__ C) {        // [MDIM][NDIM]
  // 4 slots x (A 8192 u16) = 64 KiB
  __shared__ __attribute__((aligned(16))) u16 As[4 * 8192];

  const int tid  = threadIdx.x;
  const int lane = tid & 63;
  const int wv   = tid >> 6;
  const int wm   = wv >> 2;       // 0..1  (M wave row)
  const int wn   = wv & 3;        // 0..3  (N wave col)
  const int quad = lane >> 4;     // 0..3
  const int l16  = lane & 15;

  // XCD-aware bijective swizzle: 512 wgs, 8 XCDs, 64 contiguous per XCD.
  const int orig    = blockIdx.y * 16 + blockIdx.x;
  const int wg      = (orig & 7) * 64 + (orig >> 3);
  const int rowBase = (wg >> 4) * 256;   // M
  const int colBase = (wg & 15) * 256;   // N

  // A staging: thread covers slot-chunks c = tid and tid+512 (1024 x 16B/slot).
  // Global source pre-swizzled: row = c>>2, kchunk = (c&3) ^ ((row>>1)&3).
  const u16* gA[2];
  int sOff[2];
#pragma unroll
  for (int j = 0; j < 2; ++j) {
    int c  = j * 512 + tid;
    int r  = c >> 2;
    int qg = (c & 3) ^ ((r >> 1) & 3);
    gA[j]   = Xb + (size_t)(rowBase + r) * KDIM + qg * 8;
    sOff[j] = c * 8;  // u16 elements within a slot
  }

#define STAGE_A(s, kt)                                              \
  do {                                                              \
    load_lds16(gA[0] + (kt), (u16*)As + (s) * 8192 + sOff[0]);      \
    load_lds16(gA[1] + (kt), (u16*)As + (s) * 8192 + sOff[1]);      \
  } while (0)

  // B global fragment base pointers (per-lane): col = wn*64 + j*16 + l16,
  // k-chunk = quad*8. Identical bytes the old LDS B path delivered.
  const u16* gB[4];
#pragma unroll
  for (int j = 0; j < 4; ++j) {
    gB[j] = Qb + (size_t)(colBase + wn * 64 + j * 16 + l16) * KDIM + quad * 8;
  }

#define LOAD_B(BN, kt)                                              \
  do {                                                              \
    BN[0] = *(const bf16x8*)(gB[0] + (kt));                         \
    BN[1] = *(const bf16x8*)(gB[1] + (kt));                         \
    BN[2] = *(const bf16x8*)(gB[2] + (kt));                         \
    BN[3] = *(const bf16x8*)(gB[3] + (kt));                         \
  } while (0)

  // A fragment LDS element offsets (slot-relative), swizzle-matched.
  int ac[8];
#pragma unroll
  for (int i = 0; i < 8; ++i) {
    int r = wm * 128 + i * 16 + l16;
    ac[i] = (r * 4 + (quad ^ ((r >> 1) & 3))) * 8;
  }

#define RD_A(d, i, s) d = *(const bf16x8*)((const u16*)As + (s) * 8192 + ac[i])

  f32x4 acc[8][4] = {};
  bf16x8 a0[4], a1[4], ab[4], b0[4], b1[4];

  // Prologue: stage A tiles 0,1,2 into slots 0,1,2 (6 glds); load B(0) regs.
  STAGE_A(0, 0);
  STAGE_A(1, 32);
  STAGE_A(2, 64);
  FENCE();
  LOAD_B(b0, 0);
  VMCNT8();            // in-order: retires A(0) (newest 8 = A(1),A(2),B(0))
  FENCE(); BARRIER(); FENCE();
  // Preload tile 0 A-fragments (slot 0, Mreps 0-3).
  RD_A(a0[0], 0, 0); RD_A(a0[1], 1, 0); RD_A(a0[2], 2, 0); RD_A(a0[3], 3, 0);

  // Tile body: S, frag sets, and PRE are compile-time (4x unrolled ring).
#define TILE(S, AC, BC, AN, BN, PRE)                                       \
  do {                                                                     \
    const int kt  = (t + 3 < NTILE) ? (t + 3) * 32 : 0;                    \
    const int kbn = (t + 1 < NTILE) ? (t + 1) * 32 : 0;                    \
    STAGE_A(((S) + 3) & 3, kt);                                            \
    FENCE();                                                               \
    LOAD_B(BN, kbn);                                                       \
    RD_A(ab[0], 4, S); RD_A(ab[1], 5, S);                                  \
    RD_A(ab[2], 6, S); RD_A(ab[3], 7, S);                                  \
    __builtin_amdgcn_s_setprio(1);                                         \
    MFMA16(AC, BC, 0);                                                     \
    __builtin_amdgcn_s_setprio(0);                                         \
    if (PRE) {                                                             \
      RD_A(AN[0], 0, ((S) + 1) & 3); RD_A(AN[1], 1, ((S) + 1) & 3);        \
      RD_A(AN[2], 2, ((S) + 1) & 3); RD_A(AN[3], 3, ((S) + 1) & 3);        \
    }                                                                      \
    __builtin_amdgcn_s_setprio(1);                                         \
    MFMA16(ab, BC, 4);                                                     \
    __builtin_amdgcn_s_setprio(0);                                         \
    VMCNT6();                                                              \
    FENCE(); BARRIER(); FENCE();                                           \
    ++t;                                                                   \
  } while (0)

  int t = 0;
  for (int it = 0; it < NTILE / 4 - 1; ++it) {   // 31 iters = tiles 0..123
    TILE(0, a0, b0, a1, b1, 1);
    TILE(1, a1, b1, a0, b0, 1);
    TILE(2, a0, b0, a1, b1, 1);
    TILE(3, a1, b1, a0, b0, 1);
  }
  TILE(0, a0, b0, a1, b1, 1);   // t = 124
  TILE(1, a1, b1, a0, b0, 1);   // t = 125
  TILE(2, a0, b0, a1, b1, 1);   // t = 126  (preloads tile 127 A, slot 3)
  TILE(3, a1, b1, a0, b0, 0);   // t = 127  (no A preload; dummy B(k=0) load)

  // Epilogue: C/D layout col = lane&15, row = quad*4 + reg (verified)
  float bv[4];
#pragma unroll
  for (int j = 0; j < 4; ++j) bv[j] = bias[colBase + wn * 64 + j * 16 + l16];

#pragma unroll
  for (int i = 0; i < 8; ++i) {
#pragma unroll
    for (int r = 0; r < 4; ++r) {
      int grow = rowBase + wm * 128 + i * 16 + quad * 4 + r;
      float* crow = C + (size_t)grow * NDIM + colBase + wn * 64 + l16;
#pragma unroll
      for (int j = 0; j < 4; ++j) {
        crow[j * 16] = acc[i][j][r] + bv[j];
      }
    }
  }
}

// ---------------------------------------------------------------- launch ----

extern "C" void kernel_launch(void* const* d_in, const int* in_sizes, int n_in,
                              void* d_out, int out_size, void* d_ws, size_t ws_size,
                              hipStream_t stream) {
  const float* x    = (const float*)d_in[0];
  const float* w    = (const float*)d_in[1];
  const float* bias = (const float*)d_in[2];
  float* out = (float*)d_out;

  // workspace: Xb bf16 [MDIM*KDIM] then Qb bf16 [NDIM*KDIM]  (= 100.7 MB)
  u16* xb = (u16*)d_ws;
  u16* qb = xb + (size_t)MDIM * KDIM;

  cvt_kernel<<<(unsigned)(XBLOCKS + WBLOCKS), 256, 0, stream>>>(x, xb, w, qb);

  dim3 grid(NDIM / 256, MDIM / 256);   // (16, 32)
  gemm_tern_kernel<<<grid, 512, 0, stream>>>(xb, qb, bias, out);
}